// Round 14
// baseline (28.886 us; speedup 1.0000x reference)
//
#include <hip/hip_runtime.h>

#define NUM_LABELS 20
#define N_PIX 4096
#define C_DIM 16
#define BATCH 4

#define PTILE 128
#define PNT (N_PIX / PTILE)               // 32
#define PTPAIRS (PNT * (PNT + 1) / 2)     // 528
#define PREP_SLICES 16                    // prep blocks per batch (64 total)
#define NPREP (BATCH * PREP_SLICES)
#define KPAD 24                           // LDS row stride in shorts (48 B)

typedef __attribute__((ext_vector_type(8))) short bf16x8;
typedef __attribute__((ext_vector_type(4))) float f32x4;

__device__ __forceinline__ unsigned int bf16rne(float f) {
    unsigned int x = __float_as_uint(f);
    return (x + 0x7fffu + ((x >> 16) & 1u)) >> 16;
}

// ---------------- Kernel A: ballot hist + normalize -> gT; extras; out=0 ----
// g = (1/cnt[y]) * normalize(center(x))
// part[blk] = -0.5*sum_slice |g_f32|^2  (+ 0.5*#present for slice-0 blocks)
__global__ __launch_bounds__(256) void prep_kernel(
    const float* __restrict__ emb,         // [B][C][N]
    const int*   __restrict__ lab,         // [B][N]
    unsigned short* __restrict__ gT,       // [B][N][C] bf16
    float* __restrict__ part,              // [NPREP]
    float* __restrict__ out)               // [1]
{
    const int blk  = blockIdx.x;
    const int b    = blk / PREP_SLICES;
    const int sl   = blk % PREP_SLICES;
    const int t    = threadIdx.x;
    const int wv   = t >> 6;
    const int lane = t & 63;

    if (blk == 0 && t == 0) out[0] = 0.f;   // zeroed before node-2 atomics

    __shared__ int   h[NUM_LABELS];
    __shared__ float rinv[NUM_LABELS];
    __shared__ float wsum[4];

    if (t < NUM_LABELS) h[t] = 0;
    __syncthreads();

    {   // ballot histogram of this batch's 4096 labels (wave wv covers 1024)
        const int* yb = lab + (size_t)b * N_PIX;
        int cnt[NUM_LABELS];
#pragma unroll
        for (int l = 0; l < NUM_LABELS; ++l) cnt[l] = 0;
        for (int it = 0; it < 16; ++it) {
            const int y = yb[wv * 1024 + it * 64 + lane];
#pragma unroll
            for (int l = 0; l < NUM_LABELS; ++l)
                cnt[l] += (int)__popcll(__ballot(y == l));
        }
        if (lane == 0) {
#pragma unroll
            for (int l = 0; l < NUM_LABELS; ++l) atomicAdd(&h[l], cnt[l]);
        }
    }
    __syncthreads();
    if (t < NUM_LABELS) rinv[t] = (h[t] > 0) ? 1.0f / (float)h[t] : 0.0f;
    __syncthreads();

    // normalize one pixel per thread (coalesced per-channel loads)
    const int n = sl * 256 + t;
    const float* xb = emb + (size_t)b * C_DIM * N_PIX + n;
    float v[C_DIM];
    float s = 0.f;
#pragma unroll
    for (int c = 0; c < C_DIM; ++c) { v[c] = xb[(size_t)c * N_PIX]; s += v[c]; }
    const float mean = s * (1.0f / C_DIM);
    float ss = 0.f;
#pragma unroll
    for (int c = 0; c < C_DIM; ++c) { v[c] -= mean; ss += v[c] * v[c]; }
    const float nrm = sqrtf(ss);
    const float w   = rinv[lab[(size_t)b * N_PIX + n]];
    const float inv = (nrm > 0.f) ? (w / nrm) : 0.f;

    unsigned int u[8];
#pragma unroll
    for (int k = 0; k < 8; ++k) {
        const unsigned int lo = bf16rne(v[2 * k] * inv);
        const unsigned int hi = bf16rne(v[2 * k + 1] * inv);
        u[k] = lo | (hi << 16);
    }
    unsigned int* gp = (unsigned int*)(gT + ((size_t)b * N_PIX + n) * C_DIM);
    *reinterpret_cast<uint4*>(gp)     = make_uint4(u[0], u[1], u[2], u[3]);
    *reinterpret_cast<uint4*>(gp + 4) = make_uint4(u[4], u[5], u[6], u[7]);

    // -0.5 * sum |g_f32|^2 over this slice (+ present term on slice 0)
    float sq = inv * inv * ss;
#pragma unroll
    for (int off = 32; off > 0; off >>= 1) sq += __shfl_down(sq, off);
    if (lane == 0) wsum[wv] = sq;
    __syncthreads();
    if (t == 0) {
        float e = -0.5f * (wsum[0] + wsum[1] + wsum[2] + wsum[3]);
        if (sl == 0) {
            int p = 0;
#pragma unroll
            for (int l = 0; l < NUM_LABELS; ++l) p += (h[l] > 0) ? 1 : 0;
            e += 0.5f * (float)p;
        }
        part[blk] = e;
    }
}

// ---------------- Kernel B: 528 blocks x 512 thr; one tile-pair x 4 batches -
// block partial = sum_b sum_{i<j in tile-pair} (eq ? -s : max(s,0))
// block 0 folds the 64 prep extras.  out += partial / N (one atomic/block).
__global__ __launch_bounds__(512) void pair_kernel(
    const unsigned short* __restrict__ gT, // [B][N][C] bf16
    const int*   __restrict__ lab,         // [B][N]
    const float* __restrict__ part,        // [NPREP]
    float* __restrict__ out)               // [1]
{
    const int k0 = blockIdx.x;             // tile-pair id, same for all batches

    // decode upper-triangle tile pair (ti <= tj)
    const float nn = (float)PNT;
    int ti = (int)(((2.f * nn + 1.f) -
                    sqrtf((2.f * nn + 1.f) * (2.f * nn + 1.f) - 8.f * (float)k0)) * 0.5f);
    if (ti < 0) ti = 0;
    if (ti > PNT - 1) ti = PNT - 1;
    auto rowoff = [](int r) { return r * PNT - (r * (r - 1)) / 2; };
    while (ti > 0 && k0 < rowoff(ti)) --ti;
    while (ti < PNT - 1 && k0 >= rowoff(ti + 1)) ++ti;
    const int tj = ti + (k0 - rowoff(ti));
    const bool diag = (ti == tj);

    const int t    = threadIdx.x;
    const int wv   = t >> 6;               // 0..7 (one rtile per wave)
    const int lane = t & 63;
    const int lo16 = lane & 15;
    const int hi   = lane >> 4;            // 0..3
    const bool doread = (hi < 2);          // K=16 real; hi>=2 lanes hold zeros

    __shared__ unsigned short sI[PTILE * KPAD];
    __shared__ unsigned short sJ[PTILE * KPAD];
    __shared__ int   syI[PTILE], syJ[PTILE];
    __shared__ float wred[8];

    float sum = 0.f;

    // block 0: fold prep extras (independent of LDS)
    if (k0 == 0 && t < NPREP) {
        float e = part[t];
#pragma unroll
        for (int off = 32; off > 0; off >>= 1) e += __shfl_down(e, off);
        if (t == 0) sum += e;
    }

    for (int b = 0; b < BATCH; ++b) {
        __syncthreads();   // previous batch's LDS reads complete

        // ---- stage this batch's two bf16 tiles + labels --------------------
        const unsigned short* gb = gT + (size_t)b * N_PIX * C_DIM;
        {
            const int u2  = t & 255;
            const int row = u2 >> 1, half = u2 & 1;
            const int tile = (t < 256) ? ti : tj;
            unsigned short* dst = (t < 256) ? sI : sJ;
            const uint4 vv = *(reinterpret_cast<const uint4*>(
                gb + (size_t)(tile * PTILE + row) * C_DIM) + half);
            *reinterpret_cast<uint4*>(&dst[row * KPAD + half * 8]) = vv;
        }
        if (t < PTILE) {
            syI[t] = lab[(size_t)b * N_PIX + ti * PTILE + t];
        } else if (t < 2 * PTILE) {
            const int u = t - PTILE;
            syJ[u] = lab[(size_t)b * N_PIX + tj * PTILE + u];
        }
        __syncthreads();

        // ---- MFMA + epilogue (wave wv owns rtile = wv) ---------------------
        const int rtile = wv;
        bf16x8 afrag = bf16x8{};
        if (doread)
            afrag = *reinterpret_cast<const bf16x8*>(&sI[(rtile * 16 + lo16) * KPAD + hi * 8]);
        int yIr[4];
        {
            const int4 yv = *reinterpret_cast<const int4*>(&syI[rtile * 16 + hi * 4]);
            yIr[0] = yv.x; yIr[1] = yv.y; yIr[2] = yv.z; yIr[3] = yv.w;
        }

#pragma unroll
        for (int ct = 0; ct < 8; ++ct) {
            if (diag && rtile > ct) continue;      // below diagonal: skip
            bf16x8 bfrag = bf16x8{};
            if (doread)
                bfrag = *reinterpret_cast<const bf16x8*>(&sJ[(ct * 16 + lo16) * KPAD + hi * 8]);
            const int yq = syJ[ct * 16 + lo16];
            f32x4 acc = {0.f, 0.f, 0.f, 0.f};
            acc = __builtin_amdgcn_mfma_f32_16x16x32_bf16(afrag, bfrag, acc, 0, 0, 0);
            if (diag && rtile == ct) {
#pragma unroll
                for (int j = 0; j < 4; ++j) {
                    const float s = acc[j];
                    const float v = (yIr[j] == yq) ? -s : fmaxf(s, 0.f);
                    const int iloc = hi * 4 + j;
                    sum += (iloc < lo16) ? v : 0.f;   // strict i<j
                }
            } else {
#pragma unroll
                for (int j = 0; j < 4; ++j) {
                    const float s = acc[j];
                    sum += (yIr[j] == yq) ? -s : fmaxf(s, 0.f);
                }
            }
        }
    }

    // ---- block reduction (8 waves) + one atomic -----------------------------
#pragma unroll
    for (int off = 32; off > 0; off >>= 1) sum += __shfl_down(sum, off);
    if (lane == 0) wred[wv] = sum;
    __syncthreads();
    if (t == 0) {
        float total = 0.f;
#pragma unroll
        for (int i = 0; i < 8; ++i) total += wred[i];
        atomicAdd(out, total * (1.0f / (float)N_PIX));
    }
}

extern "C" void kernel_launch(void* const* d_in, const int* in_sizes, int n_in,
                              void* d_out, int out_size, void* d_ws, size_t ws_size,
                              hipStream_t stream) {
    const float* emb = (const float*)d_in[0];
    const int*   lab = (const int*)d_in[1];
    float* out = (float*)d_out;

    unsigned short* gT = (unsigned short*)d_ws;                    // B*N*C bf16
    float* part = (float*)(gT + (size_t)BATCH * N_PIX * C_DIM);    // NPREP floats

    prep_kernel<<<NPREP, 256, 0, stream>>>(emb, lab, gT, part, out);
    pair_kernel<<<PTPAIRS, 512, 0, stream>>>(gT, lab, part, out);
}